// Round 1
// 499.690 us; speedup vs baseline: 1.0802x; 1.0802x over previous
//
#include <hip/hip_runtime.h>

#define BATCH 16
#define LSEQ 2048
#define DIM 64
#define TQ 32            // q rows per block (main kernel)
#define SSTRIDE 2056     // halfs; 16B-aligned row stride, bank-spread (+8)
#define EPSV 1e-8f
#define SCALE_LOG2E 0.18033688011112042f   // log2(e) / 8

typedef float f4 __attribute__((ext_vector_type(4)));
typedef _Float16 h4 __attribute__((ext_vector_type(4)));
typedef _Float16 h8 __attribute__((ext_vector_type(8)));
typedef int i4t __attribute__((ext_vector_type(4)));

__device__ inline h8 cvt_h8(f4 a, f4 b) {
    h8 r;
    r[0] = (_Float16)a[0]; r[1] = (_Float16)a[1];
    r[2] = (_Float16)a[2]; r[3] = (_Float16)a[3];
    r[4] = (_Float16)b[0]; r[5] = (_Float16)b[1];
    r[6] = (_Float16)b[2]; r[7] = (_Float16)b[3];
    return r;
}

// ---- preprocess: K fp32 -> fp16 row-major (straight cvt, coalesced) ----
__global__ __launch_bounds__(256)
void cvt_k_kernel(const float* __restrict__ k, _Float16* __restrict__ kh) {
    const int idx = blockIdx.x * 256 + threadIdx.x;   // f4 index; total 524288
    f4 v = ((const f4*)k)[idx];
    h4 h;
    #pragma unroll
    for (int e = 0; e < 4; ++e) h[e] = (_Float16)v[e];
    ((h4*)kh)[idx] = h;
}

// ---- preprocess: V fp32 [b][k][d] -> fp16 transposed Vt [b][d][k] ----
__global__ __launch_bounds__(256)
void tr_v_kernel(const float* __restrict__ v, _Float16* __restrict__ vt) {
    __shared__ float tile[64][65];
    const int b = blockIdx.y, k0 = blockIdx.x * 64, t = threadIdx.x;
    const float* vb = v + ((size_t)b * LSEQ + k0) * DIM;
    #pragma unroll
    for (int p = 0; p < 4; ++p) {
        const int row = p * 16 + (t >> 4), c4 = (t & 15) * 4;
        f4 val = *(const f4*)(vb + row * DIM + c4);
        #pragma unroll
        for (int e = 0; e < 4; ++e) tile[row][c4 + e] = val[e];
    }
    __syncthreads();
    _Float16* vtb = vt + (size_t)b * DIM * LSEQ;
    #pragma unroll
    for (int p = 0; p < 4; ++p) {
        const int d = p * 16 + (t >> 4), k4 = (t & 15) * 4;
        h4 h;
        #pragma unroll
        for (int e = 0; e < 4; ++e) h[e] = (_Float16)tile[k4 + e][d];
        *(h4*)(vtb + (size_t)d * LSEQ + k0 + k4) = h;
    }
}

// ---- main kernel: TQ=32, 16 waves, ~148 KB LDS, 1 block/CU ----
// Halves per-iteration L2 traffic (Kh/Vt each read once per 32 q-rows
// instead of once per 16). Mask rows prefetched into VGPRs so the HBM
// latency of the masked-renorm phase hides under QK^T / barriers.
__global__ __launch_bounds__(1024, 4)
void attn_kernel(const float* __restrict__ q, const _Float16* __restrict__ kh,
                 const _Float16* __restrict__ vt, const int* __restrict__ mask,
                 float* __restrict__ out, float* __restrict__ attn)
{
    __shared__ __align__(16) _Float16 s_p[TQ][SSTRIDE];   // 131584 B: scores -> P
    __shared__ float oacc[16][256];                        // 16384 B: PV partials
    __shared__ float s_inv[TQ];                            // 128 B

    const int b    = blockIdx.y;
    const int q0   = blockIdx.x * TQ;
    const int tid  = threadIdx.x;
    const int w    = tid >> 6;     // 0..15
    const int lane = tid & 63;
    const int quad = lane >> 4;
    const int m16  = lane & 15;

    // ---- mask prefetch, row 0 of this wave's pair (overlaps Phase B) ----
    const int row0 = 2 * w;
    const int* mrow0 = mask + ((size_t)b * LSEQ + q0 + row0) * LSEQ;
    i4t mv0[8];
    #pragma unroll
    for (int j = 0; j < 8; ++j)
        mv0[j] = __builtin_nontemporal_load((const i4t*)(mrow0 + lane * 4 + 256 * j));

    // ---- Q A-frags for both 16-row q-tiles (fp32 -> h8 once) ----
    const float* qrowA = q + ((size_t)b * LSEQ + q0 + m16) * DIM + quad * 8;
    const float* qrowB = qrowA + 16 * DIM;
    h8 aqA0 = cvt_h8(*(const f4*)(qrowA),      *(const f4*)(qrowA + 4));
    h8 aqA1 = cvt_h8(*(const f4*)(qrowA + 32), *(const f4*)(qrowA + 36));
    h8 aqB0 = cvt_h8(*(const f4*)(qrowB),      *(const f4*)(qrowB + 4));
    h8 aqB1 = cvt_h8(*(const f4*)(qrowB + 32), *(const f4*)(qrowB + 36));

    // ---- Phase B: S' = (QK^T) * log2(e)/8 -> LDS fp16.
    //      Each wave does 8 k-tiles; bk frags shared by both q-tiles (4 MFMA/tile).
    for (int t = w; t < LSEQ / 16; t += 16) {
        const int c = t * 16;
        const _Float16* krow = kh + ((size_t)b * LSEQ + c + m16) * DIM + quad * 8;
        h8 bk0 = *(const h8*)(krow);
        h8 bk1 = *(const h8*)(krow + 32);
        f4 accA = {0.f, 0.f, 0.f, 0.f}, accB = {0.f, 0.f, 0.f, 0.f};
        accA = __builtin_amdgcn_mfma_f32_16x16x32_f16(aqA0, bk0, accA, 0, 0, 0);
        accA = __builtin_amdgcn_mfma_f32_16x16x32_f16(aqA1, bk1, accA, 0, 0, 0);
        accB = __builtin_amdgcn_mfma_f32_16x16x32_f16(aqB0, bk0, accB, 0, 0, 0);
        accB = __builtin_amdgcn_mfma_f32_16x16x32_f16(aqB1, bk1, accB, 0, 0, 0);
        #pragma unroll
        for (int r = 0; r < 4; ++r) {
            s_p[quad * 4 + r][c + m16]      = (_Float16)(accA[r] * SCALE_LOG2E);
            s_p[16 + quad * 4 + r][c + m16] = (_Float16)(accB[r] * SCALE_LOG2E);
        }
    }
    __syncthreads();

    // ---- prefetch row 1's mask (hides under row 0 processing) ----
    const int* mrow1 = mrow0 + LSEQ;
    i4t mv1[8];
    #pragma unroll
    for (int j = 0; j < 8; ++j)
        mv1[j] = __builtin_nontemporal_load((const i4t*)(mrow1 + lane * 4 + 256 * j));

    // ---- Phase C/D: exp2, masked renorm, attn write, P -> LDS fp16 ----
    #pragma unroll
    for (int rr = 0; rr < 2; ++rr) {
        const int row = 2 * w + rr;
        float sa = 0.f, sk = 0.f;
        h4 pk[8];
        #pragma unroll
        for (int j = 0; j < 8; ++j) {
            h4 hv = *(const h4*)(&s_p[row][lane * 4 + 256 * j]);
            i4t m = rr ? mv1[j] : mv0[j];
            #pragma unroll
            for (int e = 0; e < 4; ++e) {
                float p = exp2f((float)hv[e]);   // scores pre-scaled by log2(e)/8
                sa += p;
                float pm = m[e] ? 0.f : p;
                sk += pm;
                pk[j][e] = (_Float16)pm;
            }
        }
        #pragma unroll
        for (int off = 32; off >= 1; off >>= 1) {
            sa += __shfl_xor(sa, off);
            sk += __shfl_xor(sk, off);
        }
        const float inv_d = 1.f / (sk + EPSV * sa);
        if (lane == 0) s_inv[row] = inv_d;

        float* arow = attn + ((size_t)b * LSEQ + q0 + row) * LSEQ;
        #pragma unroll
        for (int j = 0; j < 8; ++j) {
            const int c = lane * 4 + 256 * j;
            *(h4*)(&s_p[row][c]) = pk[j];
            f4 pv;
            #pragma unroll
            for (int e = 0; e < 4; ++e) pv[e] = inv_d * (float)pk[j][e];
            __builtin_nontemporal_store(pv, (f4*)(&arow[c]));
        }
    }
    __syncthreads();

    // ---- Phase E: O_unnorm = P V via Vt, Vt read once per block.
    //      wave -> (d-tile = w&3, k-quarter = w>>2); both q-tiles per wave.
    const int dt = w & 3;
    const int kq = w >> 2;
    const _Float16* vtr = vt + ((size_t)b * DIM + dt * 16 + m16) * LSEQ;
    f4 accA = {0.f, 0.f, 0.f, 0.f}, accB = {0.f, 0.f, 0.f, 0.f};
    #pragma unroll 2
    for (int kb = kq * 512; kb < kq * 512 + 512; kb += 32) {
        const int kk = kb + quad * 8;
        h8 bf  = *(const h8*)(vtr + kk);
        h8 afA = *(const h8*)(&s_p[m16][kk]);
        h8 afB = *(const h8*)(&s_p[16 + m16][kk]);
        accA = __builtin_amdgcn_mfma_f32_16x16x32_f16(afA, bf, accA, 0, 0, 0);
        accB = __builtin_amdgcn_mfma_f32_16x16x32_f16(afB, bf, accB, 0, 0, 0);
    }

    float* ob = out + ((size_t)b * LSEQ + q0) * DIM;

    // stage 1: rows 0..15
    #pragma unroll
    for (int r = 0; r < 4; ++r)
        oacc[w][(quad * 4 + r) * 16 + m16] = accA[r];
    __syncthreads();
    {
        const int row = tid >> 6;         // 0..15
        const int d   = tid & 63;
        const int dt2 = d >> 4, dc = d & 15;
        const int o   = row * 16 + dc;
        float vsum = oacc[dt2][o] + oacc[4 + dt2][o]
                   + oacc[8 + dt2][o] + oacc[12 + dt2][o];
        ob[row * DIM + d] = s_inv[row] * vsum;
    }
    __syncthreads();

    // stage 2: rows 16..31
    #pragma unroll
    for (int r = 0; r < 4; ++r)
        oacc[w][(quad * 4 + r) * 16 + m16] = accB[r];
    __syncthreads();
    {
        const int row = tid >> 6;
        const int d   = tid & 63;
        const int dt2 = d >> 4, dc = d & 15;
        const int o   = row * 16 + dc;
        float vsum = oacc[dt2][o] + oacc[4 + dt2][o]
                   + oacc[8 + dt2][o] + oacc[12 + dt2][o];
        ob[(16 + row) * DIM + d] = s_inv[16 + row] * vsum;
    }
}

// ---- fallback (TQ=16, raw fp32 K/V; used only if d_ws is too small) ----
__global__ __launch_bounds__(512, 4)
void attn_kernel_fb(const float* __restrict__ q, const float* __restrict__ k,
                    const float* __restrict__ v, const int* __restrict__ mask,
                    float* __restrict__ out, float* __restrict__ attn)
{
    __shared__ __align__(16) _Float16 s_p[16][SSTRIDE];
    __shared__ float oacc[8][16 * 16];
    __shared__ float s_inv[16];

    const int b = blockIdx.y, q0 = blockIdx.x * 16, tid = threadIdx.x;
    const int w = tid >> 6, lane = tid & 63, quad = lane >> 4, m16 = lane & 15;
    const float* kp = k + (size_t)b * LSEQ * DIM;
    const float* vp = v + (size_t)b * LSEQ * DIM;
    const float* qrow = q + ((size_t)b * LSEQ + q0 + m16) * DIM + quad * 8;
    h8 aq0 = cvt_h8(*(const f4*)(qrow),      *(const f4*)(qrow + 4));
    h8 aq1 = cvt_h8(*(const f4*)(qrow + 32), *(const f4*)(qrow + 36));

    for (int t = w; t < LSEQ / 16; t += 8) {
        const int c = t * 16;
        const float* krow = kp + (size_t)(c + m16) * DIM + quad * 8;
        h8 bk0 = cvt_h8(*(const f4*)(krow),      *(const f4*)(krow + 4));
        h8 bk1 = cvt_h8(*(const f4*)(krow + 32), *(const f4*)(krow + 36));
        f4 acc = {0.f, 0.f, 0.f, 0.f};
        acc = __builtin_amdgcn_mfma_f32_16x16x32_f16(aq0, bk0, acc, 0, 0, 0);
        acc = __builtin_amdgcn_mfma_f32_16x16x32_f16(aq1, bk1, acc, 0, 0, 0);
        #pragma unroll
        for (int r = 0; r < 4; ++r)
            s_p[quad * 4 + r][c + m16] = (_Float16)(acc[r] * 0.125f);
    }
    __syncthreads();

    #pragma unroll
    for (int rr = 0; rr < 2; ++rr) {
        const int row = 2 * w + rr;
        const int* mrow = mask + ((size_t)b * LSEQ + q0 + row) * LSEQ;
        i4t mv[8];
        #pragma unroll
        for (int j = 0; j < 8; ++j)
            mv[j] = __builtin_nontemporal_load((const i4t*)(mrow + lane * 4 + 256 * j));
        float sa = 0.f, sk = 0.f;
        h4 pk[8];
        #pragma unroll
        for (int j = 0; j < 8; ++j) {
            h4 hv = *(const h4*)(&s_p[row][lane * 4 + 256 * j]);
            #pragma unroll
            for (int e = 0; e < 4; ++e) {
                float p = __expf((float)hv[e]);
                sa += p;
                float pm = mv[j][e] ? 0.f : p;
                sk += pm;
                pk[j][e] = (_Float16)pm;
            }
        }
        #pragma unroll
        for (int off = 32; off >= 1; off >>= 1) {
            sa += __shfl_xor(sa, off);
            sk += __shfl_xor(sk, off);
        }
        const float inv_d = 1.f / (sk + EPSV * sa);
        if (lane == 0) s_inv[row] = inv_d;
        float* arow = attn + ((size_t)b * LSEQ + q0 + row) * LSEQ;
        #pragma unroll
        for (int j = 0; j < 8; ++j) {
            const int c = lane * 4 + 256 * j;
            *(h4*)(&s_p[row][c]) = pk[j];
            f4 pv;
            #pragma unroll
            for (int e = 0; e < 4; ++e) pv[e] = inv_d * (float)pk[j][e];
            __builtin_nontemporal_store(pv, (f4*)(&arow[c]));
        }
    }
    __syncthreads();

    {
        const int dt = w >> 1, kh_ = w & 1;
        f4 acc = {0.f, 0.f, 0.f, 0.f};
        for (int kb0 = kh_ * 1024; kb0 < kh_ * 1024 + 1024; kb0 += 32) {
            const int kk = kb0 + quad * 8;
            h8 af = *(const h8*)(&s_p[m16][kk]);
            const float* vcol = vp + (size_t)kk * DIM + dt * 16 + m16;
            h8 bf;
            #pragma unroll
            for (int j = 0; j < 8; ++j) bf[j] = (_Float16)vcol[j * DIM];
            acc = __builtin_amdgcn_mfma_f32_16x16x32_f16(af, bf, acc, 0, 0, 0);
        }
        #pragma unroll
        for (int r = 0; r < 4; ++r)
            oacc[w][(quad * 4 + r) * 16 + m16] = acc[r];
    }
    __syncthreads();

    float* ob = out + ((size_t)b * LSEQ + q0) * DIM;
    #pragma unroll
    for (int it = 0; it < 2; ++it) {
        const int idx = tid + it * 512;
        const int row = idx >> 6, d = idx & 63;
        const int dt2 = d >> 4, dc = d & 15;
        ob[row * DIM + d] = s_inv[row] *
            (oacc[2 * dt2][row * 16 + dc] + oacc[2 * dt2 + 1][row * 16 + dc]);
    }
}

extern "C" void kernel_launch(void* const* d_in, const int* in_sizes, int n_in,
                              void* d_out, int out_size, void* d_ws, size_t ws_size,
                              hipStream_t stream) {
    const float* q = (const float*)d_in[0];
    const float* k = (const float*)d_in[1];
    const float* v = (const float*)d_in[2];
    const int* mask = (const int*)d_in[3];
    float* out = (float*)d_out;
    float* attn = out + (size_t)BATCH * LSEQ * DIM;

    const size_t kv_elems = (size_t)BATCH * LSEQ * DIM;
    if (ws_size >= kv_elems * 2 * sizeof(_Float16)) {
        _Float16* kh = (_Float16*)d_ws;
        _Float16* vt = kh + kv_elems;
        cvt_k_kernel<<<kv_elems / 4 / 256, 256, 0, stream>>>(k, kh);
        tr_v_kernel<<<dim3(LSEQ / 64, BATCH), 256, 0, stream>>>(v, vt);
        attn_kernel<<<dim3(LSEQ / TQ, BATCH), 1024, 0, stream>>>(q, kh, vt, mask, out, attn);
    } else {
        attn_kernel_fb<<<dim3(LSEQ / 16, BATCH), 512, 0, stream>>>(q, k, v, mask, out, attn);
    }
}